// Round 7
// baseline (395.514 us; speedup 1.0000x reference)
//
#include <hip/hip_runtime.h>
#include <math.h>

#define Bb 2
#define Ss 576
#define Ff 16
#define Hh 8
#define Cc 64
#define HC 512
#define Mrows (Bb * Ss * Ff)   // 18432

typedef __bf16 bf16x8 __attribute__((ext_vector_type(8)));
typedef float  f32x4  __attribute__((ext_vector_type(4)));
typedef float  f32x16 __attribute__((ext_vector_type(16)));
typedef unsigned short u16;
typedef unsigned int   u32;

#if __has_builtin(__builtin_amdgcn_exp2f)
#define EXP2(x) __builtin_amdgcn_exp2f(x)
#else
#define EXP2(x) exp2f(x)
#endif

// q pre-scale: 1/sqrt(C) * log2(e), folded into the q GEMM epilogue
#define QSCALE 0.18033688011112042f

__device__ __forceinline__ u16 f2bf(float f) {
    union { __bf16 b; u16 u; } cv;
    cv.b = (__bf16)f;          // hardware RNE convert
    return cv.u;
}

__device__ __forceinline__ f32x16 zero16() {
    f32x16 z;
#pragma unroll
    for (int i = 0; i < 16; ++i) z[i] = 0.f;
    return z;
}

// XOR swizzle for attn LDS
__device__ __forceinline__ int swz8(int row, int g) {   // 64-u16 rows
    return row * 64 + (((g ^ (row & 7) ^ (((row >> 3) & 1) << 1)) & 7) << 3);
}

__device__ __forceinline__ uint4 pack8(float4 a, float4 b) {
    union { u16 s[8]; uint4 v; } u;
    u.s[0] = f2bf(a.x); u.s[1] = f2bf(a.y); u.s[2] = f2bf(a.z); u.s[3] = f2bf(a.w);
    u.s[4] = f2bf(b.x); u.s[5] = f2bf(b.y); u.s[6] = f2bf(b.z); u.s[7] = f2bf(b.w);
    return u.v;
}

// async global->LDS, 16 B per lane; LDS dest must be linear in lane order.
__device__ __forceinline__ void gl_lds16(const u16* g, u16* l) {
    __builtin_amdgcn_global_load_lds(
        (const __attribute__((address_space(1))) u32*)g,
        (__attribute__((address_space(3))) u32*)l, 16, 0, 0);
}

// ---------------------------------------------------------------------------
// Fused prep: z<4 -> transpose+convert one weight matrix (Wt[mat][n][k]);
// z>=4 -> streaming fp32->bf16 conversion of an x chunk.
// Also zeroes the 80 split-K merge counters (one block).
// grid dim3(8, 8, 4 + 72): 72*64 = 4608 x-chunks of 2048 elems.
// ---------------------------------------------------------------------------
__global__ __launch_bounds__(256) void prep_kernel(
    const float* __restrict__ W0, const float* __restrict__ W1,
    const float* __restrict__ W2, const float* __restrict__ W3,
    const float* __restrict__ x,
    u16* __restrict__ Wt, u16* __restrict__ xb, int* __restrict__ cnt)
{
    __shared__ float Ts[64][65];
    const int mz = blockIdx.z;
    const int t = threadIdx.x;
    if (mz >= 4) {
        if (mz == 4 && blockIdx.x == 0 && blockIdx.y == 0 && t < 80) cnt[t] = 0;
        int id = (mz - 4) * 64 + blockIdx.y * 8 + blockIdx.x;
        size_t i = ((size_t)id * 256 + t) * 8;
        float4 a = *(const float4*)&x[i];
        float4 b = *(const float4*)&x[i + 4];
        *(uint4*)&xb[i] = pack8(a, b);
        return;
    }
    const float* W = (mz == 0) ? W0 : (mz == 1) ? W1 : (mz == 2) ? W2 : W3;
    u16* Wo = Wt + (size_t)mz * 512 * 512;
    const int k0 = blockIdx.x * 64, n0 = blockIdx.y * 64;
#pragma unroll
    for (int p = 0; p < 4; ++p) {
        int idx = t + p * 256;
        int row = idx >> 4, cg = idx & 15;
        *(float4*)&Ts[row][cg * 4] =
            *(const float4*)&W[(size_t)(k0 + row) * 512 + n0 + cg * 4];
    }
    __syncthreads();
#pragma unroll
    for (int p = 0; p < 2; ++p) {
        int idx = t + p * 256;
        int row = idx >> 3, cg = idx & 7;   // row = local n
        union { u16 s[8]; uint4 v; } u;
#pragma unroll
        for (int j = 0; j < 8; ++j) u.s[j] = f2bf(Ts[cg * 8 + j][row]);
        *(uint4*)&Wo[(size_t)(n0 + row) * 512 + k0 + cg * 8] = u.v;
    }
}

// ---------------------------------------------------------------------------
// Fused QKV GEMM — round-3 single-buffer m97 structure (verified 56.7 µs).
// ---------------------------------------------------------------------------
__global__ __launch_bounds__(256) void qkv_kernel(
    const u16* __restrict__ xb, const u16* __restrict__ Wt,
    u16* __restrict__ q, u16* __restrict__ k, u16* __restrict__ vT)
{
    __shared__ u16 As[128 * 32];
    __shared__ u16 Bs[128 * 32];
    const int bi = blockIdx.x;
    const int mt = bi % 144;
    const int mm = bi / 144;
    const int nt = mm & 3, mat = mm >> 2;
    const int t = threadIdx.x;
    const int w = t >> 6, L = t & 63;
    const int m0 = mt * 128, n0 = nt * 128;
    const int wm = (w >> 1) * 64, wn = (w & 1) * 64;

    const int srow = t >> 2, scg = t & 3;
    const int ma0 = m0 + srow, ma1 = ma0 + 64;
    const int b0 = ma0 / 9216, r0 = ma0 % 9216, f0 = r0 / 576, s0 = r0 % 576;
    const int b1 = ma1 / 9216, r1 = ma1 % 9216, f1 = r1 / 576, s1 = r1 % 576;
    const u16* xp0 = xb + ((size_t)(b0 * 576 + s0) * 16 + f0) * 512 + scg * 8;
    const u16* xp1 = xb + ((size_t)(b1 * 576 + s1) * 16 + f1) * 512 + scg * 8;
    const u16* Bp = Wt + (size_t)mat * 512 * 512 + (size_t)(n0 + srow) * 512 + scg * 8;

    f32x4 acc[4][4];
#pragma unroll
    for (int i = 0; i < 4; ++i)
#pragma unroll
        for (int j = 0; j < 4; ++j) acc[i][j] = (f32x4){0.f, 0.f, 0.f, 0.f};

    for (int k0 = 0; k0 < 512; k0 += 32) {
        __syncthreads();
        gl_lds16(xp0 + k0, &As[t * 8]);              // rows 0..63
        gl_lds16(xp1 + k0, &As[2048 + t * 8]);       // rows 64..127
        gl_lds16(Bp + k0, &Bs[t * 8]);
        gl_lds16(Bp + k0 + 64 * 512, &Bs[2048 + t * 8]);
        __syncthreads();                             // vmcnt(0) drain here
        bf16x8 af[4], bfr[4];
#pragma unroll
        for (int i = 0; i < 4; ++i) {
            af[i]  = *(const bf16x8*)&As[(wm + 16 * i + (L & 15)) * 32 + (L >> 4) * 8];
            bfr[i] = *(const bf16x8*)&Bs[(wn + 16 * i + (L & 15)) * 32 + (L >> 4) * 8];
        }
#pragma unroll
        for (int i = 0; i < 4; ++i)
#pragma unroll
            for (int j = 0; j < 4; ++j)
                acc[i][j] = __builtin_amdgcn_mfma_f32_16x16x32_bf16(
                    af[i], bfr[j], acc[i][j], 0, 0, 0);
    }

    if (mat < 2) {
        u16* Cout = (mat == 0) ? q : k;
        const float scale = (mat == 0) ? QSCALE : 1.0f;
#pragma unroll
        for (int i = 0; i < 4; ++i)
#pragma unroll
            for (int j = 0; j < 4; ++j)
#pragma unroll
                for (int r = 0; r < 4; ++r) {
                    int row = m0 + wm + 16 * i + (L >> 4) * 4 + r;
                    int col = n0 + wn + 16 * j + (L & 15);
                    float vv = acc[i][j][r] * scale;
                    float pvv = __shfl_xor(vv, 1);
                    if (!(L & 1)) {
                        u32 pk2 = (u32)f2bf(vv) | ((u32)f2bf(pvv) << 16);
                        *(u32*)(Cout + (size_t)row * 512 + col) = pk2;
                    }
                }
    } else {
#pragma unroll
        for (int i = 0; i < 4; ++i) {
            int row = m0 + wm + 16 * i + (L >> 4) * 4;   // s aligned to 4
            int bb = row / 9216, rr = row % 9216;
            int f = rr / 576, s = rr % 576;
#pragma unroll
            for (int j = 0; j < 4; ++j) {
                int col = n0 + wn + 16 * j + (L & 15);
                int h = col >> 6, c = col & 63;
                union { u16 s4[4]; uint2 v; } u;
#pragma unroll
                for (int r = 0; r < 4; ++r) u.s4[r] = f2bf(acc[i][j][r]);
                *(uint2*)&vT[((((size_t)(bb * 16 + f) * 8 + h) * 64 + c) * 576) + s] = u.v;
            }
        }
    }
}

// ---------------------------------------------------------------------------
// Output GEMM — round-3 single-buffer m97 structure.
// ---------------------------------------------------------------------------
__global__ __launch_bounds__(256) void gemm_out_kernel(
    const u16* __restrict__ res, const u16* __restrict__ Wt3,
    const float* __restrict__ bout, float* __restrict__ out)
{
    __shared__ u16 As[128 * 32];
    __shared__ u16 Bs[128 * 32];
    const int bi = blockIdx.x;
    const int mt = bi % 144, nt = bi / 144;
    const int t = threadIdx.x;
    const int w = t >> 6, L = t & 63;
    const int m0 = mt * 128, n0 = nt * 128;
    const int wm = (w >> 1) * 64, wn = (w & 1) * 64;

    const int srow = t >> 2, scg = t & 3;
    const u16* Ap = res + (size_t)(m0 + srow) * 512 + scg * 8;
    const u16* Bp = Wt3 + (size_t)(n0 + srow) * 512 + scg * 8;

    f32x4 acc[4][4];
#pragma unroll
    for (int i = 0; i < 4; ++i)
#pragma unroll
        for (int j = 0; j < 4; ++j) acc[i][j] = (f32x4){0.f, 0.f, 0.f, 0.f};

    for (int k0 = 0; k0 < 512; k0 += 32) {
        __syncthreads();
        gl_lds16(Ap + k0, &As[t * 8]);
        gl_lds16(Ap + k0 + 64 * 512, &As[2048 + t * 8]);
        gl_lds16(Bp + k0, &Bs[t * 8]);
        gl_lds16(Bp + k0 + 64 * 512, &Bs[2048 + t * 8]);
        __syncthreads();
        bf16x8 af[4], bfr[4];
#pragma unroll
        for (int i = 0; i < 4; ++i) {
            af[i]  = *(const bf16x8*)&As[(wm + 16 * i + (L & 15)) * 32 + (L >> 4) * 8];
            bfr[i] = *(const bf16x8*)&Bs[(wn + 16 * i + (L & 15)) * 32 + (L >> 4) * 8];
        }
#pragma unroll
        for (int i = 0; i < 4; ++i)
#pragma unroll
            for (int j = 0; j < 4; ++j)
                acc[i][j] = __builtin_amdgcn_mfma_f32_16x16x32_bf16(
                    af[i], bfr[j], acc[i][j], 0, 0, 0);
    }

#pragma unroll
    for (int i = 0; i < 4; ++i)
#pragma unroll
        for (int r = 0; r < 4; ++r) {
            int row = m0 + wm + 16 * i + (L >> 4) * 4 + r;
            int bb = row / 9216, rr = row % 9216;
            int f = rr / 576, s = rr % 576;
            size_t obase = ((size_t)(bb * 576 + s) * 16 + f) * 512;
#pragma unroll
            for (int j = 0; j < 4; ++j) {
                int col = n0 + wn + 16 * j + (L & 15);
                out[obase + col] = acc[i][j][r] + bout[col];
            }
        }
}

// ---------------------------------------------------------------------------
// MFMA flash attention — round-3 structure + fused split-K merge:
// the 9th-arriving mode-0 block of each (bh,qt) group merges the partials
// and writes res[f=0] directly (merge_kernel eliminated).
// Release: per-thread __threadfence before the device-scope atomicAdd.
// Acquire: __threadfence after observing old==8, before reading peers' po.
// ---------------------------------------------------------------------------
__global__ __launch_bounds__(256, 4) void attn_kernel(
    const u16* __restrict__ q, const u16* __restrict__ k,
    const u16* __restrict__ vT, const int* __restrict__ dm,
    u16* __restrict__ res, float* __restrict__ po, float* __restrict__ pl,
    int* __restrict__ cnt)
{
    __shared__ u16 Ks[64 * 64];    // [key][c]  swizzled
    __shared__ u16 Vts[64 * 64];   // [c][key]  swizzled
    __shared__ int sflag;

    const int t = threadIdx.x;
    const int w = t >> 6, L = t & 63;
    const int half = L >> 5, l31 = L & 31;
    const int bi = blockIdx.x;

    int b, h, qt, qframe, fi, mode;
    if (bi < 720) {                 // mode0: bid = qt*144 + (bh*9 + fi)
        mode = 0;
        qt = bi / 144;
        int g = bi % 144;           // 144 ≡ 0 mod 8 -> (bh,fi) XCD-congruent
        int bh = g / 9; fi = g % 9;
        b = bh >> 3; h = bh & 7; qframe = 0;
    } else {
        mode = 1;
        int u = bi - 720;
        int g = u % 240;            // 240 ≡ 0 mod 8
        qt = u / 240;
        b = g / 120;
        int rr = g % 120;
        qframe = 1 + (rr >> 3); h = rr & 7; fi = 0;
    }

    // per-thread keyframe resolve (uniform scalar loads, no LDS / barrier)
    int kf;
    if (mode == 1) {
        kf = qframe;
    } else if (fi < 2) {
        kf = fi;
    } else {
        int n = 2; kf = 2;
#pragma unroll
        for (int j = 0; j < Ff - 2; ++j) {
            if (dm[b * (Ff - 2) + j] == 0) { if (n == fi) kf = 2 + j; ++n; }
        }
    }

    const int q0 = qt * 128;
    const bool active = (q0 + 32 * w) < Ss;
    const int qrow = q0 + 32 * w + l31;       // global query row (if active)

    // Q B-frags: B[n=q=l31][k=c=16*ks+8*half+j], direct from global
    bf16x8 qf[4];
    if (active) {
        const u16* qp = q + ((size_t)(b * 16 + qframe) * Ss + qrow) * 512 + h * 64 + 8 * half;
#pragma unroll
        for (int ks = 0; ks < 4; ++ks) qf[ks] = *(const bf16x8*)(qp + 16 * ks);
    }

    float lsum = 0.f;
    f32x16 o[2] = {zero16(), zero16()};

    const int srow = t >> 2, sc2 = (t & 3) * 2;
    const int lk0 = swz8(srow, sc2), lk1 = swz8(srow, sc2 + 1);
    const u16* kbase = k + ((size_t)(b * 16 + kf) * Ss) * 512 + h * 64;
    const u16* vbase = vT + (((size_t)(b * 16 + kf) * 8 + h) * 64) * (size_t)Ss;

    uint4 ka, kb2, va, vb2;
    {
        const u16* kp = kbase + (size_t)srow * 512 + sc2 * 8;
        ka  = *(const uint4*)kp;
        kb2 = *(const uint4*)(kp + 8);
        const u16* vp = vbase + (size_t)srow * Ss + sc2 * 8;
        va  = *(const uint4*)vp;
        vb2 = *(const uint4*)(vp + 8);
    }

    for (int kt = 0; kt < 9; ++kt) {
        __syncthreads();
        *(uint4*)&Ks[lk0]  = ka;
        *(uint4*)&Ks[lk1]  = kb2;
        *(uint4*)&Vts[lk0] = va;
        *(uint4*)&Vts[lk1] = vb2;
        __syncthreads();

        if (kt < 8) {
            int s0 = (kt + 1) * 64;
            const u16* kp = kbase + (size_t)(s0 + srow) * 512 + sc2 * 8;
            ka  = *(const uint4*)kp;
            kb2 = *(const uint4*)(kp + 8);
            const u16* vp = vbase + (size_t)srow * Ss + s0 + sc2 * 8;
            va  = *(const uint4*)vp;
            vb2 = *(const uint4*)(vp + 8);
        }

        if (active) {
#pragma unroll
            for (int hb = 0; hb < 2; ++hb) {
                // S^T m-tile hb (keys 32*hb..32*hb+31): A=K frags, B=Q frags
                f32x16 st = zero16();
#pragma unroll
                for (int ks = 0; ks < 4; ++ks) {
                    bf16x8 a = *(const bf16x8*)&Ks[swz8(32 * hb + l31, 2 * ks + half)];
                    st = __builtin_amdgcn_mfma_f32_32x32x16_bf16(a, qf[ks], st, 0, 0, 0);
                }
                // P = 2^s -> bf16 B-frags fully in-register (no Ps LDS)
#pragma unroll
                for (int kk = 0; kk < 2; ++kk) {
                    const int ks = 2 * hb + kk;   // PV key-chunk index
                    float e0 = EXP2(st[8 * kk + 0]), e1 = EXP2(st[8 * kk + 1]);
                    float e2 = EXP2(st[8 * kk + 2]), e3 = EXP2(st[8 * kk + 3]);
                    float e4 = EXP2(st[8 * kk + 4]), e5 = EXP2(st[8 * kk + 5]);
                    float e6 = EXP2(st[8 * kk + 6]), e7 = EXP2(st[8 * kk + 7]);
                    lsum += ((e0 + e1) + (e2 + e3)) + ((e4 + e5) + (e6 + e7));
                    u32 x0 = (u32)f2bf(e0) | ((u32)f2bf(e1) << 16);
                    u32 z0 = (u32)f2bf(e2) | ((u32)f2bf(e3) << 16);
                    u32 x1 = (u32)f2bf(e4) | ((u32)f2bf(e5) << 16);
                    u32 z1 = (u32)f2bf(e6) | ((u32)f2bf(e7) << 16);
                    auto sx = __builtin_amdgcn_permlane32_swap(x0, x1, false, false);
                    auto sz = __builtin_amdgcn_permlane32_swap(z0, z1, false, false);
                    union { u32 u[4]; bf16x8 v; } pu;
                    pu.u[0] = sx[0]; pu.u[1] = sz[0]; pu.u[2] = sx[1]; pu.u[3] = sz[1];
                    bf16x8 v0 = *(const bf16x8*)&Vts[swz8(l31,      2 * ks + half)];
                    bf16x8 v1 = *(const bf16x8*)&Vts[swz8(32 + l31, 2 * ks + half)];
                    o[0] = __builtin_amdgcn_mfma_f32_32x32x16_bf16(v0, pu.v, o[0], 0, 0, 0);
                    o[1] = __builtin_amdgcn_mfma_f32_32x32x16_bf16(v1, pu.v, o[1], 0, 0, 0);
                }
            }
        }
    }

    if (mode == 1) {
        if (!active) return;
        lsum += __shfl_xor(lsum, 32);
        float inv = 1.f / lsum;
        u16* rp = res + ((size_t)(b * 16 + qframe) * Ss + qrow) * 512 + h * 64;
#pragma unroll
        for (int cg = 0; cg < 2; ++cg)
#pragma unroll
            for (int g = 0; g < 4; ++g) {
                union { u16 s4[4]; uint2 v; } u;
#pragma unroll
                for (int r = 0; r < 4; ++r) u.s4[r] = f2bf(o[cg][4 * g + r] * inv);
                *(uint2*)&rp[32 * cg + 8 * g + 4 * half] = u.v;
            }
        return;
    }

    // ---- mode0: write fp32 partials, then last-arriving block merges ----
    const int bh2 = b * 8 + h;
    if (active) {
        lsum += __shfl_xor(lsum, 32);
        float* pp = po + ((size_t)(fi * 16 + bh2) * Ss + qrow) * 64;
#pragma unroll
        for (int cg = 0; cg < 2; ++cg)
#pragma unroll
            for (int g = 0; g < 4; ++g) {
                float4 v4 = make_float4(o[cg][4 * g + 0], o[cg][4 * g + 1],
                                        o[cg][4 * g + 2], o[cg][4 * g + 3]);
                *(float4*)&pp[32 * cg + 8 * g + 4 * half] = v4;
            }
        if (half == 0) pl[(size_t)(fi * 16 + bh2) * Ss + qrow] = lsum;
    }

    __threadfence();                 // release partials (device scope)
    __syncthreads();
    if (t == 0) sflag = atomicAdd(&cnt[qt * 16 + bh2], 1);
    __syncthreads();
    if (sflag != 8) return;          // not the last block of this group

    __threadfence();                 // acquire: see peers' partials
    const int c4 = t & 15;
    const int rloc = t >> 4;         // 0..15
#pragma unroll
    for (int p = 0; p < 8; ++p) {
        int qg = q0 + p * 16 + rloc;
        if (qg < Ss) {
            float4 acc2 = make_float4(0.f, 0.f, 0.f, 0.f);
            float ls = 0.f;
#pragma unroll
            for (int f2 = 0; f2 < 9; ++f2) {
                const float4 v = *(const float4*)&po[((size_t)(f2 * 16 + bh2) * Ss + qg) * 64 + c4 * 4];
                acc2.x += v.x; acc2.y += v.y; acc2.z += v.z; acc2.w += v.w;
                ls += pl[(size_t)(f2 * 16 + bh2) * Ss + qg];
            }
            float inv = 1.f / ls;
            union { u16 s4[4]; uint2 v; } u;
            u.s4[0] = f2bf(acc2.x * inv); u.s4[1] = f2bf(acc2.y * inv);
            u.s4[2] = f2bf(acc2.z * inv); u.s4[3] = f2bf(acc2.w * inv);
            *(uint2*)&res[((size_t)(b * 16 + 0) * Ss + qg) * 512 + h * 64 + c4 * 4] = u.v;
        }
    }
}

// ---------------------------------------------------------------------------
extern "C" void kernel_launch(void* const* d_in, const int* in_sizes, int n_in,
                              void* d_out, int out_size, void* d_ws, size_t ws_size,
                              hipStream_t stream)
{
    (void)in_sizes; (void)n_in; (void)out_size; (void)ws_size;
    const float* x    = (const float*)d_in[0];
    const int*   dmsk = (const int*)  d_in[1];
    const float* Wq   = (const float*)d_in[2];
    const float* Wk   = (const float*)d_in[3];
    const float* Wv   = (const float*)d_in[4];
    const float* Wout = (const float*)d_in[5];
    const float* bout = (const float*)d_in[6];
    float* out = (float*)d_out;

    const size_t NE = (size_t)Mrows * HC;   // 9437184
    u16* q   = (u16*)d_ws;                  // [b,f,s,hc]
    u16* kk  = q   + NE;                    // [b,f,s,hc]
    u16* vT  = kk  + NE;                    // [b,f,h,c,s]
    u16* res = vT  + NE;                    // [b,f,s,hc]
    u16* Wt  = res + NE;                    // 4 x 512x512 (n-major)
    float* po = (float*)(Wt + (size_t)4 * 512 * 512);   // [9][16][576][64]
    float* pl = po + (size_t)9 * 16 * Ss * 64;          // [9][16][576]
    int* cnt = (int*)(pl + (size_t)9 * 16 * Ss);        // 80 split-K counters
    // xb (bf16 x) aliases res: res is first written by attn_kernel, which runs
    // after qkv_kernel has finished reading xb (same stream, ordered).
    u16* xb = res;

    prep_kernel<<<dim3(8, 8, 76), 256, 0, stream>>>(Wq, Wk, Wv, Wout, x, Wt, xb, cnt);
    qkv_kernel<<<1728, 256, 0, stream>>>(xb, Wt, q, kk, vT);
    attn_kernel<<<1920, 256, 0, stream>>>(q, kk, vT, dmsk, res, po, pl, cnt);
    gemm_out_kernel<<<576, 256, 0, stream>>>(
        res, Wt + (size_t)3 * 512 * 512, bout, out);
}

// Round 8
// 214.295 us; speedup vs baseline: 1.8456x; 1.8456x over previous
//
#include <hip/hip_runtime.h>
#include <math.h>

#define Bb 2
#define Ss 576
#define Ff 16
#define Hh 8
#define Cc 64
#define HC 512
#define Mrows (Bb * Ss * Ff)   // 18432

typedef __bf16 bf16x8 __attribute__((ext_vector_type(8)));
typedef float  f32x4  __attribute__((ext_vector_type(4)));
typedef float  f32x16 __attribute__((ext_vector_type(16)));
typedef unsigned short u16;
typedef unsigned int   u32;

#if __has_builtin(__builtin_amdgcn_exp2f)
#define EXP2(x) __builtin_amdgcn_exp2f(x)
#else
#define EXP2(x) exp2f(x)
#endif

// q pre-scale: 1/sqrt(C) * log2(e), folded into the q GEMM epilogue
#define QSCALE 0.18033688011112042f

__device__ __forceinline__ u16 f2bf(float f) {
    union { __bf16 b; u16 u; } cv;
    cv.b = (__bf16)f;          // hardware RNE convert
    return cv.u;
}

__device__ __forceinline__ f32x16 zero16() {
    f32x16 z;
#pragma unroll
    for (int i = 0; i < 16; ++i) z[i] = 0.f;
    return z;
}

// XOR swizzle for attn LDS
__device__ __forceinline__ int swz8(int row, int g) {   // 64-u16 rows
    return row * 64 + (((g ^ (row & 7) ^ (((row >> 3) & 1) << 1)) & 7) << 3);
}

__device__ __forceinline__ uint4 pack8(float4 a, float4 b) {
    union { u16 s[8]; uint4 v; } u;
    u.s[0] = f2bf(a.x); u.s[1] = f2bf(a.y); u.s[2] = f2bf(a.z); u.s[3] = f2bf(a.w);
    u.s[4] = f2bf(b.x); u.s[5] = f2bf(b.y); u.s[6] = f2bf(b.z); u.s[7] = f2bf(b.w);
    return u.v;
}

// async global->LDS, 16 B per lane; LDS dest must be linear in lane order.
__device__ __forceinline__ void gl_lds16(const u16* g, u16* l) {
    __builtin_amdgcn_global_load_lds(
        (const __attribute__((address_space(1))) u32*)g,
        (__attribute__((address_space(3))) u32*)l, 16, 0, 0);
}

// ---------------------------------------------------------------------------
// Fused prep: z<4 -> transpose+convert one weight matrix (Wt[mat][n][k]);
// z>=4 -> streaming fp32->bf16 conversion of an x chunk.
// grid dim3(8, 8, 4 + 72): 72*64 = 4608 x-chunks of 2048 elems.
// ---------------------------------------------------------------------------
__global__ __launch_bounds__(256) void prep_kernel(
    const float* __restrict__ W0, const float* __restrict__ W1,
    const float* __restrict__ W2, const float* __restrict__ W3,
    const float* __restrict__ x,
    u16* __restrict__ Wt, u16* __restrict__ xb)
{
    __shared__ float Ts[64][65];
    const int mz = blockIdx.z;
    const int t = threadIdx.x;
    if (mz >= 4) {
        int id = (mz - 4) * 64 + blockIdx.y * 8 + blockIdx.x;
        size_t i = ((size_t)id * 256 + t) * 8;
        float4 a = *(const float4*)&x[i];
        float4 b = *(const float4*)&x[i + 4];
        *(uint4*)&xb[i] = pack8(a, b);
        return;
    }
    const float* W = (mz == 0) ? W0 : (mz == 1) ? W1 : (mz == 2) ? W2 : W3;
    u16* Wo = Wt + (size_t)mz * 512 * 512;
    const int k0 = blockIdx.x * 64, n0 = blockIdx.y * 64;
#pragma unroll
    for (int p = 0; p < 4; ++p) {
        int idx = t + p * 256;
        int row = idx >> 4, cg = idx & 15;
        *(float4*)&Ts[row][cg * 4] =
            *(const float4*)&W[(size_t)(k0 + row) * 512 + n0 + cg * 4];
    }
    __syncthreads();
#pragma unroll
    for (int p = 0; p < 2; ++p) {
        int idx = t + p * 256;
        int row = idx >> 3, cg = idx & 7;   // row = local n
        union { u16 s[8]; uint4 v; } u;
#pragma unroll
        for (int j = 0; j < 8; ++j) u.s[j] = f2bf(Ts[cg * 8 + j][row]);
        *(uint4*)&Wo[(size_t)(n0 + row) * 512 + k0 + cg * 8] = u.v;
    }
}

// ---------------------------------------------------------------------------
// Fused QKV GEMM — round-3 single-buffer m97 structure (verified 56.7 µs).
// ---------------------------------------------------------------------------
__global__ __launch_bounds__(256) void qkv_kernel(
    const u16* __restrict__ xb, const u16* __restrict__ Wt,
    u16* __restrict__ q, u16* __restrict__ k, u16* __restrict__ vT)
{
    __shared__ u16 As[128 * 32];
    __shared__ u16 Bs[128 * 32];
    const int bi = blockIdx.x;
    const int mt = bi % 144;
    const int mm = bi / 144;
    const int nt = mm & 3, mat = mm >> 2;
    const int t = threadIdx.x;
    const int w = t >> 6, L = t & 63;
    const int m0 = mt * 128, n0 = nt * 128;
    const int wm = (w >> 1) * 64, wn = (w & 1) * 64;

    const int srow = t >> 2, scg = t & 3;
    const int ma0 = m0 + srow, ma1 = ma0 + 64;
    const int b0 = ma0 / 9216, r0 = ma0 % 9216, f0 = r0 / 576, s0 = r0 % 576;
    const int b1 = ma1 / 9216, r1 = ma1 % 9216, f1 = r1 / 576, s1 = r1 % 576;
    const u16* xp0 = xb + ((size_t)(b0 * 576 + s0) * 16 + f0) * 512 + scg * 8;
    const u16* xp1 = xb + ((size_t)(b1 * 576 + s1) * 16 + f1) * 512 + scg * 8;
    const u16* Bp = Wt + (size_t)mat * 512 * 512 + (size_t)(n0 + srow) * 512 + scg * 8;

    f32x4 acc[4][4];
#pragma unroll
    for (int i = 0; i < 4; ++i)
#pragma unroll
        for (int j = 0; j < 4; ++j) acc[i][j] = (f32x4){0.f, 0.f, 0.f, 0.f};

    for (int k0 = 0; k0 < 512; k0 += 32) {
        __syncthreads();
        gl_lds16(xp0 + k0, &As[t * 8]);              // rows 0..63
        gl_lds16(xp1 + k0, &As[2048 + t * 8]);       // rows 64..127
        gl_lds16(Bp + k0, &Bs[t * 8]);
        gl_lds16(Bp + k0 + 64 * 512, &Bs[2048 + t * 8]);
        __syncthreads();                             // vmcnt(0) drain here
        bf16x8 af[4], bfr[4];
#pragma unroll
        for (int i = 0; i < 4; ++i) {
            af[i]  = *(const bf16x8*)&As[(wm + 16 * i + (L & 15)) * 32 + (L >> 4) * 8];
            bfr[i] = *(const bf16x8*)&Bs[(wn + 16 * i + (L & 15)) * 32 + (L >> 4) * 8];
        }
#pragma unroll
        for (int i = 0; i < 4; ++i)
#pragma unroll
            for (int j = 0; j < 4; ++j)
                acc[i][j] = __builtin_amdgcn_mfma_f32_16x16x32_bf16(
                    af[i], bfr[j], acc[i][j], 0, 0, 0);
    }

    if (mat < 2) {
        u16* Cout = (mat == 0) ? q : k;
        const float scale = (mat == 0) ? QSCALE : 1.0f;
#pragma unroll
        for (int i = 0; i < 4; ++i)
#pragma unroll
            for (int j = 0; j < 4; ++j)
#pragma unroll
                for (int r = 0; r < 4; ++r) {
                    int row = m0 + wm + 16 * i + (L >> 4) * 4 + r;
                    int col = n0 + wn + 16 * j + (L & 15);
                    float vv = acc[i][j][r] * scale;
                    float pvv = __shfl_xor(vv, 1);
                    if (!(L & 1)) {
                        u32 pk2 = (u32)f2bf(vv) | ((u32)f2bf(pvv) << 16);
                        *(u32*)(Cout + (size_t)row * 512 + col) = pk2;
                    }
                }
    } else {
#pragma unroll
        for (int i = 0; i < 4; ++i) {
            int row = m0 + wm + 16 * i + (L >> 4) * 4;   // s aligned to 4
            int bb = row / 9216, rr = row % 9216;
            int f = rr / 576, s = rr % 576;
#pragma unroll
            for (int j = 0; j < 4; ++j) {
                int col = n0 + wn + 16 * j + (L & 15);
                int h = col >> 6, c = col & 63;
                union { u16 s4[4]; uint2 v; } u;
#pragma unroll
                for (int r = 0; r < 4; ++r) u.s4[r] = f2bf(acc[i][j][r]);
                *(uint2*)&vT[((((size_t)(bb * 16 + f) * 8 + h) * 64 + c) * 576) + s] = u.v;
            }
        }
    }
}

// ---------------------------------------------------------------------------
// Output GEMM — round-3 single-buffer m97 structure.
// ---------------------------------------------------------------------------
__global__ __launch_bounds__(256) void gemm_out_kernel(
    const u16* __restrict__ res, const u16* __restrict__ Wt3,
    const float* __restrict__ bout, float* __restrict__ out)
{
    __shared__ u16 As[128 * 32];
    __shared__ u16 Bs[128 * 32];
    const int bi = blockIdx.x;
    const int mt = bi % 144, nt = bi / 144;
    const int t = threadIdx.x;
    const int w = t >> 6, L = t & 63;
    const int m0 = mt * 128, n0 = nt * 128;
    const int wm = (w >> 1) * 64, wn = (w & 1) * 64;

    const int srow = t >> 2, scg = t & 3;
    const u16* Ap = res + (size_t)(m0 + srow) * 512 + scg * 8;
    const u16* Bp = Wt3 + (size_t)(n0 + srow) * 512 + scg * 8;

    f32x4 acc[4][4];
#pragma unroll
    for (int i = 0; i < 4; ++i)
#pragma unroll
        for (int j = 0; j < 4; ++j) acc[i][j] = (f32x4){0.f, 0.f, 0.f, 0.f};

    for (int k0 = 0; k0 < 512; k0 += 32) {
        __syncthreads();
        gl_lds16(Ap + k0, &As[t * 8]);
        gl_lds16(Ap + k0 + 64 * 512, &As[2048 + t * 8]);
        gl_lds16(Bp + k0, &Bs[t * 8]);
        gl_lds16(Bp + k0 + 64 * 512, &Bs[2048 + t * 8]);
        __syncthreads();
        bf16x8 af[4], bfr[4];
#pragma unroll
        for (int i = 0; i < 4; ++i) {
            af[i]  = *(const bf16x8*)&As[(wm + 16 * i + (L & 15)) * 32 + (L >> 4) * 8];
            bfr[i] = *(const bf16x8*)&Bs[(wn + 16 * i + (L & 15)) * 32 + (L >> 4) * 8];
        }
#pragma unroll
        for (int i = 0; i < 4; ++i)
#pragma unroll
            for (int j = 0; j < 4; ++j)
                acc[i][j] = __builtin_amdgcn_mfma_f32_16x16x32_bf16(
                    af[i], bfr[j], acc[i][j], 0, 0, 0);
    }

#pragma unroll
    for (int i = 0; i < 4; ++i)
#pragma unroll
        for (int r = 0; r < 4; ++r) {
            int row = m0 + wm + 16 * i + (L >> 4) * 4 + r;
            int bb = row / 9216, rr = row % 9216;
            int f = rr / 576, s = rr % 576;
            size_t obase = ((size_t)(bb * 576 + s) * 16 + f) * 512;
#pragma unroll
            for (int j = 0; j < 4; ++j) {
                int col = n0 + wn + 16 * j + (L & 15);
                out[obase + col] = acc[i][j][r] + bout[col];
            }
        }
}

// ---------------------------------------------------------------------------
// MFMA flash attention — round-3 structure (56 µs): single-buffered 16 KB
// LDS, reg-prefetch of next tile, two barriers per k-tile. In-register P
// redistribution via bf16 packing + permlane32_swap. Partials merged by a
// separate merge_kernel — the fused split-K merge (R7) required per-block
// device-scope fences whose L2 writebacks cost ~200 µs; structurally dead.
// ---------------------------------------------------------------------------
__global__ __launch_bounds__(256, 4) void attn_kernel(
    const u16* __restrict__ q, const u16* __restrict__ k,
    const u16* __restrict__ vT, const int* __restrict__ dm,
    u16* __restrict__ res, float* __restrict__ po, float* __restrict__ pl)
{
    __shared__ u16 Ks[64 * 64];    // [key][c]  swizzled
    __shared__ u16 Vts[64 * 64];   // [c][key]  swizzled

    const int t = threadIdx.x;
    const int w = t >> 6, L = t & 63;
    const int half = L >> 5, l31 = L & 31;
    const int bi = blockIdx.x;

    int b, h, qt, qframe, fi, mode;
    if (bi < 720) {                 // mode0: bid = qt*144 + (bh*9 + fi)
        mode = 0;
        qt = bi / 144;
        int g = bi % 144;           // 144 ≡ 0 mod 8 -> (bh,fi) XCD-congruent
        int bh = g / 9; fi = g % 9;
        b = bh >> 3; h = bh & 7; qframe = 0;
    } else {
        mode = 1;
        int u = bi - 720;
        int g = u % 240;            // 240 ≡ 0 mod 8
        qt = u / 240;
        b = g / 120;
        int rr = g % 120;
        qframe = 1 + (rr >> 3); h = rr & 7; fi = 0;
    }

    // per-thread keyframe resolve (uniform scalar loads, no LDS / barrier)
    int kf;
    if (mode == 1) {
        kf = qframe;
    } else if (fi < 2) {
        kf = fi;
    } else {
        int n = 2; kf = 2;
#pragma unroll
        for (int j = 0; j < Ff - 2; ++j) {
            if (dm[b * (Ff - 2) + j] == 0) { if (n == fi) kf = 2 + j; ++n; }
        }
    }

    const int q0 = qt * 128;
    const bool active = (q0 + 32 * w) < Ss;
    const int qrow = q0 + 32 * w + l31;       // global query row (if active)

    // Q B-frags: B[n=q=l31][k=c=16*ks+8*half+j], direct from global
    bf16x8 qf[4];
    if (active) {
        const u16* qp = q + ((size_t)(b * 16 + qframe) * Ss + qrow) * 512 + h * 64 + 8 * half;
#pragma unroll
        for (int ks = 0; ks < 4; ++ks) qf[ks] = *(const bf16x8*)(qp + 16 * ks);
    }

    float lsum = 0.f;
    f32x16 o[2] = {zero16(), zero16()};

    const int srow = t >> 2, sc2 = (t & 3) * 2;
    const int lk0 = swz8(srow, sc2), lk1 = swz8(srow, sc2 + 1);
    const u16* kbase = k + ((size_t)(b * 16 + kf) * Ss) * 512 + h * 64;
    const u16* vbase = vT + (((size_t)(b * 16 + kf) * 8 + h) * 64) * (size_t)Ss;

    uint4 ka, kb2, va, vb2;
    {
        const u16* kp = kbase + (size_t)srow * 512 + sc2 * 8;
        ka  = *(const uint4*)kp;
        kb2 = *(const uint4*)(kp + 8);
        const u16* vp = vbase + (size_t)srow * Ss + sc2 * 8;
        va  = *(const uint4*)vp;
        vb2 = *(const uint4*)(vp + 8);
    }

    for (int kt = 0; kt < 9; ++kt) {
        __syncthreads();
        *(uint4*)&Ks[lk0]  = ka;
        *(uint4*)&Ks[lk1]  = kb2;
        *(uint4*)&Vts[lk0] = va;
        *(uint4*)&Vts[lk1] = vb2;
        __syncthreads();

        if (kt < 8) {
            int s0 = (kt + 1) * 64;
            const u16* kp = kbase + (size_t)(s0 + srow) * 512 + sc2 * 8;
            ka  = *(const uint4*)kp;
            kb2 = *(const uint4*)(kp + 8);
            const u16* vp = vbase + (size_t)srow * Ss + s0 + sc2 * 8;
            va  = *(const uint4*)vp;
            vb2 = *(const uint4*)(vp + 8);
        }

        if (active) {
#pragma unroll
            for (int hb = 0; hb < 2; ++hb) {
                // S^T m-tile hb (keys 32*hb..32*hb+31): A=K frags, B=Q frags
                f32x16 st = zero16();
#pragma unroll
                for (int ks = 0; ks < 4; ++ks) {
                    bf16x8 a = *(const bf16x8*)&Ks[swz8(32 * hb + l31, 2 * ks + half)];
                    st = __builtin_amdgcn_mfma_f32_32x32x16_bf16(a, qf[ks], st, 0, 0, 0);
                }
                // P = 2^s -> bf16 B-frags fully in-register (no Ps LDS)
#pragma unroll
                for (int kk = 0; kk < 2; ++kk) {
                    const int ks = 2 * hb + kk;   // PV key-chunk index
                    float e0 = EXP2(st[8 * kk + 0]), e1 = EXP2(st[8 * kk + 1]);
                    float e2 = EXP2(st[8 * kk + 2]), e3 = EXP2(st[8 * kk + 3]);
                    float e4 = EXP2(st[8 * kk + 4]), e5 = EXP2(st[8 * kk + 5]);
                    float e6 = EXP2(st[8 * kk + 6]), e7 = EXP2(st[8 * kk + 7]);
                    lsum += ((e0 + e1) + (e2 + e3)) + ((e4 + e5) + (e6 + e7));
                    u32 x0 = (u32)f2bf(e0) | ((u32)f2bf(e1) << 16);
                    u32 z0 = (u32)f2bf(e2) | ((u32)f2bf(e3) << 16);
                    u32 x1 = (u32)f2bf(e4) | ((u32)f2bf(e5) << 16);
                    u32 z1 = (u32)f2bf(e6) | ((u32)f2bf(e7) << 16);
                    auto sx = __builtin_amdgcn_permlane32_swap(x0, x1, false, false);
                    auto sz = __builtin_amdgcn_permlane32_swap(z0, z1, false, false);
                    union { u32 u[4]; bf16x8 v; } pu;
                    pu.u[0] = sx[0]; pu.u[1] = sz[0]; pu.u[2] = sx[1]; pu.u[3] = sz[1];
                    bf16x8 v0 = *(const bf16x8*)&Vts[swz8(l31,      2 * ks + half)];
                    bf16x8 v1 = *(const bf16x8*)&Vts[swz8(32 + l31, 2 * ks + half)];
                    o[0] = __builtin_amdgcn_mfma_f32_32x32x16_bf16(v0, pu.v, o[0], 0, 0, 0);
                    o[1] = __builtin_amdgcn_mfma_f32_32x32x16_bf16(v1, pu.v, o[1], 0, 0, 0);
                }
            }
        }
    }

    if (!active) return;
    lsum += __shfl_xor(lsum, 32);

    if (mode == 1) {
        float inv = 1.f / lsum;
        u16* rp = res + ((size_t)(b * 16 + qframe) * Ss + qrow) * 512 + h * 64;
#pragma unroll
        for (int cg = 0; cg < 2; ++cg)
#pragma unroll
            for (int g = 0; g < 4; ++g) {
                union { u16 s4[4]; uint2 v; } u;
#pragma unroll
                for (int r = 0; r < 4; ++r) u.s4[r] = f2bf(o[cg][4 * g + r] * inv);
                *(uint2*)&rp[32 * cg + 8 * g + 4 * half] = u.v;
            }
    } else {
        // fp32 partials for the frame-split merge (no-max softmax: just sums)
        int bh = b * 8 + h;
        float* pp = po + ((size_t)(fi * 16 + bh) * Ss + qrow) * 64;
#pragma unroll
        for (int cg = 0; cg < 2; ++cg)
#pragma unroll
            for (int g = 0; g < 4; ++g) {
                float4 v4 = make_float4(o[cg][4 * g + 0], o[cg][4 * g + 1],
                                        o[cg][4 * g + 2], o[cg][4 * g + 3]);
                *(float4*)&pp[32 * cg + 8 * g + 4 * half] = v4;
            }
        if (half == 0) pl[(size_t)(fi * 16 + bh) * Ss + qrow] = lsum;
    }
}

// ---------------------------------------------------------------------------
// Merge the 9 frame-partials of resq: res[...,frame0,...] = Σo / Σl.
// ---------------------------------------------------------------------------
__global__ __launch_bounds__(256) void merge_kernel(
    const float* __restrict__ po, const float* __restrict__ pl,
    u16* __restrict__ res)
{
    int tid = blockIdx.x * 256 + threadIdx.x;   // 147456 = 16*576*16
    int c4 = tid & 15;
    int rem = tid >> 4;
    int qg = rem % Ss;
    int bh = rem / Ss;
    int b = bh >> 3, h = bh & 7;
    float4 acc = make_float4(0.f, 0.f, 0.f, 0.f);
    float ls = 0.f;
#pragma unroll
    for (int fi = 0; fi < 9; ++fi) {
        const float4 v = *(const float4*)&po[((size_t)(fi * 16 + bh) * Ss + qg) * 64 + c4 * 4];
        acc.x += v.x; acc.y += v.y; acc.z += v.z; acc.w += v.w;
        ls += pl[(size_t)(fi * 16 + bh) * Ss + qg];
    }
    float inv = 1.f / ls;
    union { u16 s4[4]; uint2 v; } u;
    u.s4[0] = f2bf(acc.x * inv); u.s4[1] = f2bf(acc.y * inv);
    u.s4[2] = f2bf(acc.z * inv); u.s4[3] = f2bf(acc.w * inv);
    *(uint2*)&res[((size_t)(b * 16 + 0) * Ss + qg) * 512 + h * 64 + c4 * 4] = u.v;
}

// ---------------------------------------------------------------------------
extern "C" void kernel_launch(void* const* d_in, const int* in_sizes, int n_in,
                              void* d_out, int out_size, void* d_ws, size_t ws_size,
                              hipStream_t stream)
{
    (void)in_sizes; (void)n_in; (void)out_size; (void)ws_size;
    const float* x    = (const float*)d_in[0];
    const int*   dmsk = (const int*)  d_in[1];
    const float* Wq   = (const float*)d_in[2];
    const float* Wk   = (const float*)d_in[3];
    const float* Wv   = (const float*)d_in[4];
    const float* Wout = (const float*)d_in[5];
    const float* bout = (const float*)d_in[6];
    float* out = (float*)d_out;

    const size_t NE = (size_t)Mrows * HC;   // 9437184
    u16* q   = (u16*)d_ws;                  // [b,f,s,hc]
    u16* kk  = q   + NE;                    // [b,f,s,hc]
    u16* vT  = kk  + NE;                    // [b,f,h,c,s]
    u16* res = vT  + NE;                    // [b,f,s,hc]
    u16* Wt  = res + NE;                    // 4 x 512x512 (n-major)
    float* po = (float*)(Wt + (size_t)4 * 512 * 512);   // [9][16][576][64]
    float* pl = po + (size_t)9 * 16 * Ss * 64;          // [9][16][576]
    // xb (bf16 x) aliases res: res is first written by attn_kernel, which runs
    // after qkv_kernel has finished reading xb (same stream, ordered).
    u16* xb = res;

    prep_kernel<<<dim3(8, 8, 76), 256, 0, stream>>>(Wq, Wk, Wv, Wout, x, Wt, xb);
    qkv_kernel<<<1728, 256, 0, stream>>>(xb, Wt, q, kk, vT);
    attn_kernel<<<1920, 256, 0, stream>>>(q, kk, vT, dmsk, res, po, pl);
    merge_kernel<<<576, 256, 0, stream>>>(po, pl, res);
    gemm_out_kernel<<<576, 256, 0, stream>>>(
        res, Wt + (size_t)3 * 512 * 512, bout, out);
}